// Round 5
// baseline (1762.777 us; speedup 1.0000x reference)
//
#include <hip/hip_runtime.h>
#include <cmath>

#define DD 768
#define BB 32
#define NN 400
#define EE 200
#define LL 3

// padded dims for MFMA aggregation (K multiples of 32; A-row pads to tile)
#define KP1 224   // E padded (agg1 K)
#define KP2 416   // N padded (agg2 K)
#define AR1 512   // adjT row pad (N-side rows, 4 tiles of 128)
#define AR2 256   // adjF row pad (E-side rows, 2 tiles of 128)

typedef long long ll;
typedef _Float16 f16;
typedef f16 f16x8 __attribute__((ext_vector_type(8)));
typedef f16 f16x4 __attribute__((ext_vector_type(4)));
typedef float f32x4 __attribute__((ext_vector_type(4)));

// ---------------------------------------------------------------------------
// Merged split-fp16 MFMA GEMM pair: one launch computes BOTH linears that
// consume the same activation A (hi/lo f16 [M][768]):
//   blockIdx.y <  6 : "self" path  C = A @ Ws + bs            (fp32 out)
//   blockIdx.y >= 6 : "msg"  path  T = T(split((A @ Wm + bm) * rsc_row))
// 3-term Markidis (hi*hi + hi*lo + lo*hi, fp32 accum -> ~1e-6 rel error).
// W pre-transposed hi/lo f16 [e][d] (k-contiguous). 128x128 tile, BK=32,
// 4 waves (2x2), each wave 64x64 = 4x4 frags of 16x16. Row/col counts are
// exact tile multiples -> no K-loop guards. Path select is block-uniform.
// EMIT path: transpose tile in LDS (union reuse) and emit hi/lo f16
// [b][d][KPV] aggregation operands (MROWS compile-time -> magic-mul div).
// ---------------------------------------------------------------------------
template<int MROWS, int KPV>
__global__ __launch_bounds__(256)
void mfma_lin2(const f16* __restrict__ Ahi, const f16* __restrict__ Alo,
               const f16* __restrict__ Whs, const f16* __restrict__ Wls,
               const float* __restrict__ bs,
               const f16* __restrict__ Whm, const f16* __restrict__ Wlm,
               const float* __restrict__ bm,
               const float* __restrict__ rsc,
               float* __restrict__ C,
               f16* __restrict__ Th, f16* __restrict__ Tl)
{
    // staging rows padded to 40 f16 (80B): bank rotation 20 -> <=2-way (free)
    __shared__ __align__(16) union SM {
        struct { f16 As[2][128][40]; f16 Bs[2][128][40]; } k;  // 40960 B
        f16 tb[128][160];                                      // 40960 B
    } sm;
    auto& As = sm.k.As;
    auto& Bs = sm.k.Bs;

    const bool msg = (blockIdx.y >= DD / 128);
    const int n0 = (msg ? blockIdx.y - DD / 128 : blockIdx.y) * 128;
    const f16* __restrict__ Wh = msg ? Whm : Whs;
    const f16* __restrict__ Wl = msg ? Wlm : Wls;
    const float* __restrict__ bias = msg ? bm : bs;

    const int tid = threadIdx.x;
    const int lane = tid & 63, wid = tid >> 6;
    const int wr = wid >> 1, wc = wid & 1;
    const int l15 = lane & 15, lhi = lane >> 4;
    const int m0 = blockIdx.x * 128;
    const int srow = tid >> 2, sslot = tid & 3;

    f32x4 acc[4][4];
#pragma unroll
    for (int i = 0; i < 4; ++i)
#pragma unroll
        for (int j = 0; j < 4; ++j) acc[i][j] = (f32x4){0.f, 0.f, 0.f, 0.f};

    for (int k0 = 0; k0 < DD; k0 += 32) {
#pragma unroll
        for (int l = 0; l < 2; ++l) {
            const int row = srow + l * 64;
            const int kk = k0 + sslot * 8;
            const int4 va_h = *(const int4*)(Ahi + (ll)(m0 + row) * DD + kk);
            const int4 va_l = *(const int4*)(Alo + (ll)(m0 + row) * DD + kk);
            const int4 vb_h = *(const int4*)(Wh + (ll)(n0 + row) * DD + kk);
            const int4 vb_l = *(const int4*)(Wl + (ll)(n0 + row) * DD + kk);
            *(int4*)&As[0][row][sslot * 8] = va_h;
            *(int4*)&As[1][row][sslot * 8] = va_l;
            *(int4*)&Bs[0][row][sslot * 8] = vb_h;
            *(int4*)&Bs[1][row][sslot * 8] = vb_l;
        }
        __syncthreads();

        f16x8 ah[4], al[4];
#pragma unroll
        for (int m = 0; m < 4; ++m) {
            const int r = wr * 64 + m * 16 + l15;
            ah[m] = *(const f16x8*)&As[0][r][lhi * 8];
            al[m] = *(const f16x8*)&As[1][r][lhi * 8];
        }
#pragma unroll
        for (int n = 0; n < 4; ++n) {
            const int r = wc * 64 + n * 16 + l15;
            const f16x8 bh = *(const f16x8*)&Bs[0][r][lhi * 8];
            const f16x8 bl = *(const f16x8*)&Bs[1][r][lhi * 8];
#pragma unroll
            for (int m = 0; m < 4; ++m) {
                acc[m][n] = __builtin_amdgcn_mfma_f32_16x16x32_f16(ah[m], bh, acc[m][n], 0, 0, 0);
                acc[m][n] = __builtin_amdgcn_mfma_f32_16x16x32_f16(ah[m], bl, acc[m][n], 0, 0, 0);
                acc[m][n] = __builtin_amdgcn_mfma_f32_16x16x32_f16(al[m], bh, acc[m][n], 0, 0, 0);
            }
        }
        __syncthreads();
    }

    // fold bias (+ attention row-scale on msg path); fp32 C write on self path
#pragma unroll
    for (int m = 0; m < 4; ++m) {
        const int growb = m0 + wr * 64 + m * 16 + lhi * 4;
#pragma unroll
        for (int r = 0; r < 4; ++r) {
            const int grow = growb + r;
            const float rs = msg ? rsc[grow] : 1.f;
#pragma unroll
            for (int n = 0; n < 4; ++n) {
                const int gcol = n0 + wc * 64 + n * 16 + l15;
                float v = acc[m][n][r] + bias[gcol];
                if (msg) v *= rs;
                acc[m][n][r] = v;
                if (!msg) C[(ll)grow * DD + gcol] = v;
            }
        }
    }

    if (msg) {
        // two-phase LDS transpose (hi then lo), coalesced global emit
        for (int ph = 0; ph < 2; ++ph) {
            __syncthreads();   // tb free (K-loop done / prev phase read done)
#pragma unroll
            for (int m = 0; m < 4; ++m) {
#pragma unroll
                for (int n = 0; n < 4; ++n) {
                    const int col = wc * 64 + n * 16 + l15;      // output col (d)
                    const int rowb = wr * 64 + m * 16 + lhi * 4; // output row (k)
                    f16x4 pv;
#pragma unroll
                    for (int r = 0; r < 4; ++r) {
                        const float v = acc[m][n][r];
                        const f16 h = (f16)v;
                        pv[r] = (ph == 0) ? h : (f16)(v - (float)h);
                    }
                    *(f16x4*)&sm.tb[col][rowb] = pv;   // tb[d_local][k_local]
                }
            }
            __syncthreads();
            f16* T = ph ? Tl : Th;
            const int dl = tid >> 5;            // 0..7
            const int k4 = (tid & 31) * 4;      // 0..124, chunk of 4 k
#pragma unroll
            for (int it = 0; it < 16; ++it) {
                const int d_local = dl + it * 8;
                const f16x4 v = *(const f16x4*)&sm.tb[d_local][k4];
                const int gk = m0 + k4;         // global row index (b*MROWS+k)
                const int b = gk / MROWS;       // compile-time MROWS: magic mul
                const int kk = gk - b * MROWS;  // chunk never crosses batch (MROWS%4==0)
                *(f16x4*)(T + ((ll)b * DD + (n0 + d_local)) * KPV + kk) = v;
            }
        }
    }
}

// ---------------------------------------------------------------------------
// Merged MFMA aggregation (both directions in one launch):
//   blockIdx.x <  4 : ent update: C1 = relu(C1 + (adjT @ MevT^T)/colsum)
//   blockIdx.x >= 4 : ev  update: C2 = relu(C2 + (adjF @ MentT^T)/rowsum)
// A = 0/1 adjacency in f16 (exact, single term); B = hi/lo split (2-term).
// Degree normalization folded into epilogue. Optionally emits hi/lo split
// of the result for the next layer's linears. Path select block-uniform.
// ---------------------------------------------------------------------------
template<bool EMIT_SPLIT>
__global__ __launch_bounds__(256)
void mfma_agg2(const f16* __restrict__ A1, const f16* __restrict__ B1h,
               const f16* __restrict__ B1l, const float* __restrict__ ds1,
               float* __restrict__ C1, f16* __restrict__ C1hi, f16* __restrict__ C1lo,
               const f16* __restrict__ A2, const f16* __restrict__ B2h,
               const f16* __restrict__ B2l, const float* __restrict__ ds2,
               float* __restrict__ C2, f16* __restrict__ C2hi, f16* __restrict__ C2lo)
{
    __shared__ __align__(16) f16 As[128][40];
    __shared__ __align__(16) f16 Bsh[128][40];
    __shared__ __align__(16) f16 Bsl[128][40];
    const int bz = blockIdx.z;
    const bool first = (blockIdx.x < AR1 / 128);

    const f16* A;
    const f16* Bh;
    const f16* Bl;
    const float* ds;
    float* C;
    f16* Chi;
    f16* Clo;
    int M, KP, m0;
    if (first) {
        A = A1 + (ll)bz * AR1 * KP1;
        Bh = B1h + (ll)bz * DD * KP1;
        Bl = B1l + (ll)bz * DD * KP1;
        ds = ds1 + (ll)bz * NN;
        C = C1 + (ll)bz * NN * DD;
        Chi = C1hi; Clo = C1lo;
        M = NN; KP = KP1;
        m0 = blockIdx.x * 128;
    } else {
        A = A2 + (ll)bz * AR2 * KP2;
        Bh = B2h + (ll)bz * DD * KP2;
        Bl = B2l + (ll)bz * DD * KP2;
        ds = ds2 + (ll)bz * EE;
        C = C2 + (ll)bz * EE * DD;
        Chi = C2hi; Clo = C2lo;
        M = EE; KP = KP2;
        m0 = (blockIdx.x - AR1 / 128) * 128;
    }

    const int tid = threadIdx.x;
    const int lane = tid & 63, wid = tid >> 6;
    const int wr = wid >> 1, wc = wid & 1;
    const int l15 = lane & 15, lhi = lane >> 4;
    const int n0 = blockIdx.y * 128;
    const int srow = tid >> 2, sslot = tid & 3;

    f32x4 acc[4][4];
#pragma unroll
    for (int i = 0; i < 4; ++i)
#pragma unroll
        for (int j = 0; j < 4; ++j) acc[i][j] = (f32x4){0.f, 0.f, 0.f, 0.f};

    for (int k0 = 0; k0 < KP; k0 += 32) {
#pragma unroll
        for (int l = 0; l < 2; ++l) {
            const int row = srow + l * 64;
            const int kk = k0 + sslot * 8;
            *(int4*)&As[row][sslot * 8]  = *(const int4*)(A  + (ll)(m0 + row) * KP + kk);
            *(int4*)&Bsh[row][sslot * 8] = *(const int4*)(Bh + (ll)(n0 + row) * KP + kk);
            *(int4*)&Bsl[row][sslot * 8] = *(const int4*)(Bl + (ll)(n0 + row) * KP + kk);
        }
        __syncthreads();

        f16x8 av[4];
#pragma unroll
        for (int m = 0; m < 4; ++m)
            av[m] = *(const f16x8*)&As[wr * 64 + m * 16 + l15][lhi * 8];
#pragma unroll
        for (int n = 0; n < 4; ++n) {
            const int r = wc * 64 + n * 16 + l15;
            const f16x8 bh = *(const f16x8*)&Bsh[r][lhi * 8];
            const f16x8 bl = *(const f16x8*)&Bsl[r][lhi * 8];
#pragma unroll
            for (int m = 0; m < 4; ++m) {
                acc[m][n] = __builtin_amdgcn_mfma_f32_16x16x32_f16(av[m], bh, acc[m][n], 0, 0, 0);
                acc[m][n] = __builtin_amdgcn_mfma_f32_16x16x32_f16(av[m], bl, acc[m][n], 0, 0, 0);
            }
        }
        __syncthreads();
    }

#pragma unroll
    for (int m = 0; m < 4; ++m) {
        const int growb = m0 + wr * 64 + m * 16 + lhi * 4;
#pragma unroll
        for (int r = 0; r < 4; ++r) {
            const int grow = growb + r;
            if (grow >= M) continue;
            const float rs = 1.f / (ds[grow] + 1e-9f);
#pragma unroll
            for (int n = 0; n < 4; ++n) {
                const int gcol = n0 + wc * 64 + n * 16 + l15;
                float v = acc[m][n][r] * rs + C[(ll)grow * DD + gcol];
                v = fmaxf(v, 0.f);
                C[(ll)grow * DD + gcol] = v;
                if (EMIT_SPLIT) {
                    const f16 h = (f16)v;
                    const ll oi = ((ll)bz * M + grow) * DD + gcol;
                    Chi[oi] = h;
                    Clo[oi] = (f16)(v - (float)h);
                }
            }
        }
    }
}

// ---------------------------------------------------------------------------
// fp32 -> (hi,lo) f16 split, elementwise (layer-0 activations)
// ---------------------------------------------------------------------------
__global__ __launch_bounds__(256)
void split_f16(const float* __restrict__ x, f16* __restrict__ hi,
               f16* __restrict__ lo, ll n4)
{
    for (ll i = (ll)blockIdx.x * 256 + threadIdx.x; i < n4;
         i += (ll)gridDim.x * 256) {
        float4 v = ((const float4*)x)[i];
        f16 h0 = (f16)v.x, h1 = (f16)v.y, h2 = (f16)v.z, h3 = (f16)v.w;
        f16x4 hv = {h0, h1, h2, h3};
        f16x4 lv = {(f16)(v.x - (float)h0), (f16)(v.y - (float)h1),
                    (f16)(v.z - (float)h2), (f16)(v.w - (float)h3)};
        ((f16x4*)hi)[i] = hv;
        ((f16x4*)lo)[i] = lv;
    }
}

// ---------------------------------------------------------------------------
// Adjacency -> f16, both orientations, padded (0/1 exact in f16):
//   adjF[b][e][n] : [B][AR2][KP2] rows e (agg2 A), cols n zero-padded to 416
//   adjT[b][n][e] : [B][AR1][KP1] rows n (agg1 A), cols e zero-padded to 224
// Unwritten pad ROWS hold finite poison -> reach only output-guarded rows.
// ---------------------------------------------------------------------------
__global__ __launch_bounds__(256)
void adjprep(const float* __restrict__ adj, f16* __restrict__ adjF,
             f16* __restrict__ adjT)
{
    __shared__ float t[32][33];
    const int b = blockIdx.z;
    const int n0 = blockIdx.x * 32, e0 = blockIdx.y * 32;
    const int tx = threadIdx.x & 31, ty = threadIdx.x >> 5;
#pragma unroll
    for (int i = 0; i < 4; ++i) {
        const int e = e0 + ty + i * 8;
        const int n = n0 + tx;
        float v = 0.f;
        if (e < EE && n < NN) v = adj[((ll)b * EE + e) * NN + n];
        t[ty + i * 8][tx] = v;
        adjF[((ll)b * AR2 + e) * KP2 + n] = (f16)v;
    }
    __syncthreads();
#pragma unroll
    for (int i = 0; i < 4; ++i) {
        const int n = n0 + ty + i * 8;
        const int e = e0 + tx;
        adjT[((ll)b * AR1 + n) * KP1 + e] = (f16)t[tx][ty + i * 8];
    }
}

// ---------------------------------------------------------------------------
// Weight prep: transpose [d][e] fp32 -> [e][d] f16 hi/lo, 12 matrices batched
// mats 0..2 = W_ev_ent L0..2, 3..5 = W_ent_ent, 6..8 = W_ent_ev, 9..11 = W_ev_ev
// ---------------------------------------------------------------------------
__global__ __launch_bounds__(256)
void wprep(const float* __restrict__ W0, const float* __restrict__ W1,
           const float* __restrict__ W2, const float* __restrict__ W3,
           f16* __restrict__ hi, f16* __restrict__ lo)
{
    __shared__ float t[32][33];
    const int mat = blockIdx.z;
    const float* Wb = mat < 3 ? W0 : mat < 6 ? W1 : mat < 9 ? W2 : W3;
    const float* W = Wb + (ll)(mat % 3) * DD * DD;
    f16* ho = hi + (ll)mat * DD * DD;
    f16* lp = lo + (ll)mat * DD * DD;
    const int tx = threadIdx.x & 31, ty = threadIdx.x >> 5;
    const int x0 = blockIdx.x * 32, y0 = blockIdx.y * 32;
#pragma unroll
    for (int i = 0; i < 4; ++i)
        t[ty + i * 8][tx] = W[(ll)(y0 + ty + i * 8) * DD + x0 + tx];
    __syncthreads();
#pragma unroll
    for (int i = 0; i < 4; ++i) {
        const float v = t[tx][ty + i * 8];
        const f16 h = (f16)v;
        const ll idx = (ll)(x0 + ty + i * 8) * DD + y0 + tx;
        ho[idx] = h;
        lp[idx] = (f16)(v - (float)h);
    }
}

// ---------------------------------------------------------------------------
// Adjacency degree sums (denominators for the folded normalization)
// ---------------------------------------------------------------------------
__global__ __launch_bounds__(256)
void adj_sums(const float* __restrict__ adj, float* __restrict__ rowsum,
              float* __restrict__ colsum)
{
    const int b = blockIdx.x, tid = threadIdx.x;
    for (int e = tid; e < EE; e += 256) {
        const float* r = adj + ((ll)b * EE + e) * NN;
        float s = 0.f;
        for (int n = 0; n < NN; n += 4) {
            float4 v = *reinterpret_cast<const float4*>(r + n);
            s += v.x + v.y + v.z + v.w;
        }
        rowsum[b * EE + e] = s;
    }
    for (int n = tid; n < NN; n += 256) {
        float s = 0.f;
        for (int e = 0; e < EE; ++e) s += adj[((ll)b * EE + e) * NN + n];
        colsum[b * NN + n] = s;
    }
}

// ---------------------------------------------------------------------------
// Fused attention (both heads, blockIdx.y selects ev/ent):
//   att = softmax(x . (W @ sr) + b.sr)  over M
// ---------------------------------------------------------------------------
__global__ __launch_bounds__(256)
void attn2(const float* __restrict__ ev, const float* __restrict__ ent,
           const float* __restrict__ Wev, const float* __restrict__ bev,
           const float* __restrict__ Went, const float* __restrict__ bent,
           const float* __restrict__ sr,
           float* __restrict__ ev_att, float* __restrict__ ent_att)
{
    __shared__ float s_sr[DD];
    __shared__ float s_u[DD];
    __shared__ float s_log[NN];
    __shared__ float s_red[256];
    const int b = blockIdx.x, head = blockIdx.y, tid = threadIdx.x;
    const float* x = head ? ent : ev;
    const float* W = head ? Went : Wev;
    const float* bv = head ? bent : bev;
    float* att = head ? ent_att : ev_att;
    const int M = head ? NN : EE;

    for (int d = tid; d < DD; d += 256) s_sr[d] = sr[b * DD + d];
    __syncthreads();

    float cpart = 0.f;
    for (int d = tid; d < DD; d += 256) cpart += bv[d] * s_sr[d];
    for (int d = tid; d < DD; d += 256) {
        const float* wr = W + (ll)d * DD;
        float a = 0.f;
        for (int e = 0; e < DD; e += 4) {
            float4 w = *reinterpret_cast<const float4*>(wr + e);
            float4 s = *reinterpret_cast<const float4*>(s_sr + e);
            a += w.x * s.x + w.y * s.y + w.z * s.z + w.w * s.w;
        }
        s_u[d] = a;
    }
    s_red[tid] = cpart;
    __syncthreads();
    for (int off = 128; off > 0; off >>= 1) {
        if (tid < off) s_red[tid] += s_red[tid + off];
        __syncthreads();
    }
    const float c = s_red[0];
    __syncthreads();

    for (int m = tid; m < M; m += 256) {
        const float* xr = x + ((ll)b * M + m) * DD;
        float a = c;
        for (int e = 0; e < DD; e += 4) {
            float4 xv = *reinterpret_cast<const float4*>(xr + e);
            float4 uv = *reinterpret_cast<const float4*>(s_u + e);
            a += xv.x * uv.x + xv.y * uv.y + xv.z * uv.z + xv.w * uv.w;
        }
        s_log[m] = a;
    }
    __syncthreads();

    float mx = -1e30f;
    for (int m = tid; m < M; m += 256) mx = fmaxf(mx, s_log[m]);
    s_red[tid] = mx;
    __syncthreads();
    for (int off = 128; off > 0; off >>= 1) {
        if (tid < off) s_red[tid] = fmaxf(s_red[tid], s_red[tid + off]);
        __syncthreads();
    }
    const float smax = s_red[0];
    __syncthreads();

    float sum = 0.f;
    for (int m = tid; m < M; m += 256) {
        float e_ = expf(s_log[m] - smax);
        s_log[m] = e_;
        sum += e_;
    }
    s_red[tid] = sum;
    __syncthreads();
    for (int off = 128; off > 0; off >>= 1) {
        if (tid < off) s_red[tid] += s_red[tid + off];
        __syncthreads();
    }
    const float inv = 1.f / s_red[0];
    __syncthreads();
    for (int m = tid; m < M; m += 256) att[b * M + m] = s_log[m] * inv;
}

// ---------------------------------------------------------------------------
// Bilinear heads: out = x . (W @ sr) + bias ; block per (batch, head)
// ---------------------------------------------------------------------------
__global__ __launch_bounds__(256)
void heads_kernel(const float* __restrict__ ent, const float* __restrict__ ev,
                  const float* __restrict__ sr, const float* __restrict__ W_ans,
                  const float* __restrict__ b_ans, const float* __restrict__ W_evb,
                  const float* __restrict__ b_evb, float* __restrict__ out)
{
    __shared__ float s_sr[DD];
    __shared__ float s_v[DD];
    const int b = blockIdx.x, head = blockIdx.y, tid = threadIdx.x;
    const float* W = head ? W_evb : W_ans;
    const float* x = head ? ev : ent;
    const int M = head ? EE : NN;
    const float bias = head ? b_evb[0] : b_ans[0];
    float* o = out + (ll)b * (NN + EE) + (head ? NN : 0);

    for (int d = tid; d < DD; d += 256) s_sr[d] = sr[b * DD + d];
    __syncthreads();
    for (int d = tid; d < DD; d += 256) {
        const float* wr = W + (ll)d * DD;
        float a = 0.f;
        for (int e = 0; e < DD; e += 4) {
            float4 w = *reinterpret_cast<const float4*>(wr + e);
            float4 s = *reinterpret_cast<const float4*>(s_sr + e);
            a += w.x * s.x + w.y * s.y + w.z * s.z + w.w * s.w;
        }
        s_v[d] = a;
    }
    __syncthreads();
    for (int m = tid; m < M; m += 256) {
        const float* xr = x + ((ll)b * M + m) * DD;
        float a = bias;
        for (int e = 0; e < DD; e += 4) {
            float4 xv = *reinterpret_cast<const float4*>(xr + e);
            float4 vv = *reinterpret_cast<const float4*>(s_v + e);
            a += xv.x * vv.x + xv.y * vv.y + xv.z * vv.z + xv.w * vv.w;
        }
        o[m] = a;
    }
}

// ---------------------------------------------------------------------------
extern "C" void kernel_launch(void* const* d_in, const int* in_sizes, int n_in,
                              void* d_out, int out_size, void* d_ws, size_t ws_size,
                              hipStream_t stream)
{
    const float* ent_emb = (const float*)d_in[0];
    const float* ev_emb  = (const float*)d_in[1];
    const float* sr      = (const float*)d_in[2];
    const float* adj     = (const float*)d_in[3];
    const float* W_ev_att  = (const float*)d_in[4];
    const float* b_ev_att  = (const float*)d_in[5];
    const float* W_ent_att = (const float*)d_in[6];
    const float* b_ent_att = (const float*)d_in[7];
    const float* W_ev_ent  = (const float*)d_in[8];
    const float* b_ev_ent  = (const float*)d_in[9];
    const float* W_ent_ent = (const float*)d_in[10];
    const float* b_ent_ent = (const float*)d_in[11];
    const float* W_ent_ev  = (const float*)d_in[12];
    const float* b_ent_ev  = (const float*)d_in[13];
    const float* W_ev_ev   = (const float*)d_in[14];
    const float* b_ev_ev   = (const float*)d_in[15];
    const float* W_ans = (const float*)d_in[16];
    const float* b_ans = (const float*)d_in[17];
    const float* W_evb = (const float*)d_in[18];
    const float* b_evb = (const float*)d_in[19];

    float* ws = (float*)d_ws;
    ll o = 0;
    float* ent_ws = ws + o; o += (ll)BB * NN * DD;
    float* ev_ws  = ws + o; o += (ll)BB * EE * DD;
    float* ev_att  = ws + o; o += BB * EE;
    float* ent_att = ws + o; o += BB * NN;
    float* rowsum  = ws + o; o += BB * EE;
    float* colsum  = ws + o; o += BB * NN;
    o = (o + 3) & ~3LL;                              // 16B-align f16 region
    f16* fb = (f16*)(ws + o);
    ll o2 = 0;
    f16* enthi = fb + o2; o2 += (ll)BB * NN * DD;
    f16* entlo = fb + o2; o2 += (ll)BB * NN * DD;
    f16* evhi  = fb + o2; o2 += (ll)BB * EE * DD;
    f16* evlo  = fb + o2; o2 += (ll)BB * EE * DD;
    f16* WThi  = fb + o2; o2 += (ll)12 * DD * DD;
    f16* WTlo  = fb + o2; o2 += (ll)12 * DD * DD;
    f16* adjF  = fb + o2; o2 += (ll)BB * AR2 * KP2;
    f16* adjT  = fb + o2; o2 += (ll)BB * AR1 * KP1;
    f16* MevTh = fb + o2; o2 += (ll)BB * DD * KP1;
    f16* MevTl = fb + o2; o2 += (ll)BB * DD * KP1;
    f16* MentTh = fb + o2; o2 += (ll)BB * DD * KP2;
    f16* MentTl = fb + o2; o2 += (ll)BB * DD * KP2;

    const ll WS = (ll)DD * DD;
    const ll MS = (ll)DD * DD;

    adj_sums<<<BB, 256, 0, stream>>>(adj, rowsum, colsum);
    adjprep<<<dim3(KP2 / 32, KP1 / 32, BB), 256, 0, stream>>>(adj, adjF, adjT);
    wprep<<<dim3(DD / 32, DD / 32, 12), 256, 0, stream>>>(
        W_ev_ent, W_ent_ent, W_ent_ev, W_ev_ev, WThi, WTlo);
    split_f16<<<1024, 256, 0, stream>>>(ent_emb, enthi, entlo, (ll)BB * NN * DD / 4);
    split_f16<<<1024, 256, 0, stream>>>(ev_emb, evhi, evlo, (ll)BB * EE * DD / 4);

    const float* entc = ent_emb;
    const float* evc  = ev_emb;

    const dim3 gE2(BB * NN / 128, 2 * DD / 128);       // 100 x 12 (self+msg)
    const dim3 gV2(BB * EE / 128, 2 * DD / 128);       // 50 x 12
    const dim3 gAm(AR1 / 128 + AR2 / 128, DD / 128, BB); // 6 x 6 x 32

    for (int i = 0; i < LL; ++i) {
        attn2<<<dim3(BB, 2), 256, 0, stream>>>(
            evc, entc, W_ev_att + i * WS, b_ev_att + i * DD,
            W_ent_att + i * WS, b_ent_att + i * DD, sr, ev_att, ent_att);

        // ent pair: self (W_ent_ent -> ent_ws) + msg (W_ent_ev -> MentT)
        mfma_lin2<NN, KP2><<<gE2, 256, 0, stream>>>(
            enthi, entlo,
            WThi + (3 + i) * MS, WTlo + (3 + i) * MS, b_ent_ent + i * DD,
            WThi + (6 + i) * MS, WTlo + (6 + i) * MS, b_ent_ev + i * DD,
            ent_att, ent_ws, MentTh, MentTl);
        // ev pair: self (W_ev_ev -> ev_ws) + msg (W_ev_ent -> MevT)
        mfma_lin2<EE, KP1><<<gV2, 256, 0, stream>>>(
            evhi, evlo,
            WThi + (9 + i) * MS, WTlo + (9 + i) * MS, b_ev_ev + i * DD,
            WThi + (0 + i) * MS, WTlo + (0 + i) * MS, b_ev_ent + i * DD,
            ev_att, ev_ws, MevTh, MevTl);

        // merged aggregation: ent_ws = relu(ent_ws + (adjT@MevT^T)/colsum)
        //                     ev_ws  = relu(ev_ws  + (adjF@MentT^T)/rowsum)
        if (i < LL - 1) {
            mfma_agg2<true><<<gAm, 256, 0, stream>>>(
                adjT, MevTh, MevTl, colsum, ent_ws, enthi, entlo,
                adjF, MentTh, MentTl, rowsum, ev_ws, evhi, evlo);
        } else {
            mfma_agg2<false><<<gAm, 256, 0, stream>>>(
                adjT, MevTh, MevTl, colsum, ent_ws, nullptr, nullptr,
                adjF, MentTh, MentTl, rowsum, ev_ws, nullptr, nullptr);
        }

        entc = ent_ws;
        evc  = ev_ws;
    }

    heads_kernel<<<dim3(BB, 2), 256, 0, stream>>>(entc, evc, sr, W_ans, b_ans,
                                                  W_evb, b_evb, (float*)d_out);
}

// Round 6
// 1720.749 us; speedup vs baseline: 1.0244x; 1.0244x over previous
//
#include <hip/hip_runtime.h>
#include <cmath>

#define DD 768
#define BB 32
#define NN 400
#define EE 200
#define LL 3

// padded dims for MFMA aggregation (K multiples of 32; A-row pads to tile)
#define KP1 224   // E padded (agg1 K)
#define KP2 416   // N padded (agg2 K)
#define AR1 512   // adjT row pad (N-side rows, 4 tiles of 128)
#define AR2 256   // adjF row pad (E-side rows, 2 tiles of 128)

typedef long long ll;
typedef _Float16 f16;
typedef f16 f16x8 __attribute__((ext_vector_type(8)));
typedef f16 f16x4 __attribute__((ext_vector_type(4)));
typedef float f32x4 __attribute__((ext_vector_type(4)));

// async global->LDS, 16B per lane; LDS dest is wave-uniform base + lane*16
__device__ __forceinline__ void gl16(const void* g, void* l) {
    __builtin_amdgcn_global_load_lds(
        (const __attribute__((address_space(1))) unsigned int*)g,
        (__attribute__((address_space(3))) unsigned int*)l, 16, 0, 0);
}

// ---------------------------------------------------------------------------
// Merged split-fp16 MFMA GEMM (ALL FOUR relation linears in one launch):
//   blockIdx.x <  100 : ent activations (M=12800)   else ev (M=6400)
//   blockIdx.y <  6   : "self" path  C = A @ Ws + bs            (fp32 out)
//   blockIdx.y >= 6   : "msg"  path  T = T(split((A @ Wm + bm) * att_row))
// 3-term Markidis (hi*hi + hi*lo + lo*hi, fp32 accum -> ~1e-6 rel error).
// W pre-transposed hi/lo f16 [e][d] (k-contiguous). 128x128 tile, BK=32,
// 4 waves (2x2), 4x4 16x16 frags/wave. Staging via global_load_lds width=16
// into LINEAR [128][32] LDS (required: wave-uniform base + lane*16).
// All selects are block-uniform. msg path transposes the tile in LDS (union
// reuse) and emits hi/lo f16 [b][d][KPV] aggregation operands directly.
// ---------------------------------------------------------------------------
__global__ __launch_bounds__(256)
void mfma_lin4(const f16* __restrict__ entAh, const f16* __restrict__ entAl,
               const f16* __restrict__ evAh,  const f16* __restrict__ evAl,
               const f16* __restrict__ Wh_es, const f16* __restrict__ Wl_es,
               const float* __restrict__ b_es,
               const f16* __restrict__ Wh_em, const f16* __restrict__ Wl_em,
               const float* __restrict__ b_em,
               const f16* __restrict__ Wh_vs, const f16* __restrict__ Wl_vs,
               const float* __restrict__ b_vs,
               const f16* __restrict__ Wh_vm, const f16* __restrict__ Wl_vm,
               const float* __restrict__ b_vm,
               const float* __restrict__ ent_att, const float* __restrict__ ev_att,
               float* __restrict__ Cent, float* __restrict__ Cev,
               f16* __restrict__ TentH, f16* __restrict__ TentL,
               f16* __restrict__ TevH,  f16* __restrict__ TevL)
{
    __shared__ __align__(16) union SM {
        f16 stg[4][128][32];   // 0=Ah 1=Al 2=Bh 3=Bl : 32768 B (linear!)
        f16 tb[128][136];      // transpose buffer     : 34816 B
    } sm;

    const int bx = blockIdx.x;
    const bool isEnt = bx < (BB * NN / 128);
    const int xl = isEnt ? bx : bx - BB * NN / 128;
    const bool msg = (blockIdx.y >= DD / 128);
    const int n0 = (msg ? blockIdx.y - DD / 128 : blockIdx.y) * 128;
    const int m0 = xl * 128;

    const f16* __restrict__ Ah = isEnt ? entAh : evAh;
    const f16* __restrict__ Al = isEnt ? entAl : evAl;
    const f16* __restrict__ Wh = isEnt ? (msg ? Wh_em : Wh_es) : (msg ? Wh_vm : Wh_vs);
    const f16* __restrict__ Wl = isEnt ? (msg ? Wl_em : Wl_es) : (msg ? Wl_vm : Wl_vs);
    const float* __restrict__ bias = isEnt ? (msg ? b_em : b_es) : (msg ? b_vm : b_vs);
    const float* __restrict__ rsc = isEnt ? ent_att : ev_att;
    float* __restrict__ C = isEnt ? Cent : Cev;

    const int tid = threadIdx.x;
    const int lane = tid & 63, wid = tid >> 6;
    const int wr = wid >> 1, wc = wid & 1;
    const int l15 = lane & 15, lhi = lane >> 4;
    const int lr = lane >> 2;            // 0..15 row within 16-row chunk
    const int lc = (lane & 3) * 8;       // f16 col within 32-f16 row
    const int rb = wid * 32;             // wave's chunk row base (uniform)

    f32x4 acc[4][4];
#pragma unroll
    for (int i = 0; i < 4; ++i)
#pragma unroll
        for (int j = 0; j < 4; ++j) acc[i][j] = (f32x4){0.f, 0.f, 0.f, 0.f};

    for (int k0 = 0; k0 < DD; k0 += 32) {
        gl16(Ah + (ll)(m0 + rb      + lr) * DD + k0 + lc, &sm.stg[0][rb     ][0]);
        gl16(Ah + (ll)(m0 + rb + 16 + lr) * DD + k0 + lc, &sm.stg[0][rb + 16][0]);
        gl16(Al + (ll)(m0 + rb      + lr) * DD + k0 + lc, &sm.stg[1][rb     ][0]);
        gl16(Al + (ll)(m0 + rb + 16 + lr) * DD + k0 + lc, &sm.stg[1][rb + 16][0]);
        gl16(Wh + (ll)(n0 + rb      + lr) * DD + k0 + lc, &sm.stg[2][rb     ][0]);
        gl16(Wh + (ll)(n0 + rb + 16 + lr) * DD + k0 + lc, &sm.stg[2][rb + 16][0]);
        gl16(Wl + (ll)(n0 + rb      + lr) * DD + k0 + lc, &sm.stg[3][rb     ][0]);
        gl16(Wl + (ll)(n0 + rb + 16 + lr) * DD + k0 + lc, &sm.stg[3][rb + 16][0]);
        __syncthreads();   // compiler drains vmcnt before s_barrier

        f16x8 ah[4], al[4];
#pragma unroll
        for (int m = 0; m < 4; ++m) {
            const int r = wr * 64 + m * 16 + l15;
            ah[m] = *(const f16x8*)&sm.stg[0][r][lhi * 8];
            al[m] = *(const f16x8*)&sm.stg[1][r][lhi * 8];
        }
#pragma unroll
        for (int n = 0; n < 4; ++n) {
            const int r = wc * 64 + n * 16 + l15;
            const f16x8 bh = *(const f16x8*)&sm.stg[2][r][lhi * 8];
            const f16x8 bl = *(const f16x8*)&sm.stg[3][r][lhi * 8];
#pragma unroll
            for (int m = 0; m < 4; ++m) {
                acc[m][n] = __builtin_amdgcn_mfma_f32_16x16x32_f16(ah[m], bh, acc[m][n], 0, 0, 0);
                acc[m][n] = __builtin_amdgcn_mfma_f32_16x16x32_f16(ah[m], bl, acc[m][n], 0, 0, 0);
                acc[m][n] = __builtin_amdgcn_mfma_f32_16x16x32_f16(al[m], bh, acc[m][n], 0, 0, 0);
            }
        }
        __syncthreads();   // frag reads done before next stage overwrites
    }

    // fold bias (+ attention row-scale on msg path); fp32 C write (self path)
#pragma unroll
    for (int m = 0; m < 4; ++m) {
        const int growb = m0 + wr * 64 + m * 16 + lhi * 4;
#pragma unroll
        for (int r = 0; r < 4; ++r) {
            const int grow = growb + r;
            const float rs = msg ? rsc[grow] : 1.f;
#pragma unroll
            for (int n = 0; n < 4; ++n) {
                const int gcol = n0 + wc * 64 + n * 16 + l15;
                float v = acc[m][n][r] + bias[gcol];
                if (msg) v *= rs;
                acc[m][n][r] = v;
                if (!msg) C[(ll)grow * DD + gcol] = v;
            }
        }
    }

    if (msg) {
        f16* __restrict__ ThP = isEnt ? TentH : TevH;
        f16* __restrict__ TlP = isEnt ? TentL : TevL;
        const int KPV = isEnt ? KP2 : KP1;
        // two-phase LDS transpose (hi then lo), coalesced global emit
        for (int ph = 0; ph < 2; ++ph) {
            __syncthreads();   // tb free (K-loop done / prev phase read done)
#pragma unroll
            for (int m = 0; m < 4; ++m) {
#pragma unroll
                for (int n = 0; n < 4; ++n) {
                    const int col = wc * 64 + n * 16 + l15;      // output col (d)
                    const int rowb = wr * 64 + m * 16 + lhi * 4; // output row (k)
                    f16x4 pv;
#pragma unroll
                    for (int r = 0; r < 4; ++r) {
                        const float v = acc[m][n][r];
                        const f16 h = (f16)v;
                        pv[r] = (ph == 0) ? h : (f16)(v - (float)h);
                    }
                    *(f16x4*)&sm.tb[col][rowb] = pv;   // tb[d_local][k_local]
                }
            }
            __syncthreads();
            f16* T = ph ? TlP : ThP;
            const int dl = tid >> 5;            // 0..7
            const int k4 = (tid & 31) * 4;      // 0..124, chunk of 4 k
#pragma unroll
            for (int it = 0; it < 16; ++it) {
                const int d_local = dl + it * 8;
                const f16x4 v = *(const f16x4*)&sm.tb[d_local][k4];
                const int gk = m0 + k4;         // global row index (b*MROWS+k)
                const int b = isEnt ? (gk / NN) : (gk / EE);  // literal -> magic mul
                const int kk = gk - b * (isEnt ? NN : EE);    // chunks never cross batch
                *(f16x4*)(T + ((ll)b * DD + (n0 + d_local)) * KPV + kk) = v;
            }
        }
    }
}

// ---------------------------------------------------------------------------
// Merged MFMA aggregation (both directions in one launch):
//   blockIdx.x <  4 : ent update: C1 = relu(C1 + (adjT @ MevT^T)/colsum)
//   blockIdx.x >= 4 : ev  update: C2 = relu(C2 + (adjF @ MentT^T)/rowsum)
// A = 0/1 adjacency in f16 (exact, single term); B = hi/lo split (2-term).
// global_load_lds staging, linear [128][32] LDS. Degree normalization folded
// into the epilogue; optional hi/lo split emit for the next layer's linears.
// ---------------------------------------------------------------------------
template<bool EMIT_SPLIT>
__global__ __launch_bounds__(256)
void mfma_agg2(const f16* __restrict__ A1, const f16* __restrict__ B1h,
               const f16* __restrict__ B1l, const float* __restrict__ ds1,
               float* __restrict__ C1, f16* __restrict__ C1hi, f16* __restrict__ C1lo,
               const f16* __restrict__ A2, const f16* __restrict__ B2h,
               const f16* __restrict__ B2l, const float* __restrict__ ds2,
               float* __restrict__ C2, f16* __restrict__ C2hi, f16* __restrict__ C2lo)
{
    __shared__ __align__(16) f16 stg[3][128][32];   // A, Bh, Bl : 24576 B
    const int bz = blockIdx.z;
    const bool first = (blockIdx.x < AR1 / 128);

    const f16* A;
    const f16* Bh;
    const f16* Bl;
    const float* ds;
    float* C;
    f16* Chi;
    f16* Clo;
    int M, KP, m0;
    if (first) {
        A = A1 + (ll)bz * AR1 * KP1;
        Bh = B1h + (ll)bz * DD * KP1;
        Bl = B1l + (ll)bz * DD * KP1;
        ds = ds1 + (ll)bz * NN;
        C = C1 + (ll)bz * NN * DD;
        Chi = C1hi; Clo = C1lo;
        M = NN; KP = KP1;
        m0 = blockIdx.x * 128;
    } else {
        A = A2 + (ll)bz * AR2 * KP2;
        Bh = B2h + (ll)bz * DD * KP2;
        Bl = B2l + (ll)bz * DD * KP2;
        ds = ds2 + (ll)bz * EE;
        C = C2 + (ll)bz * EE * DD;
        Chi = C2hi; Clo = C2lo;
        M = EE; KP = KP2;
        m0 = (blockIdx.x - AR1 / 128) * 128;
    }

    const int tid = threadIdx.x;
    const int lane = tid & 63, wid = tid >> 6;
    const int wr = wid >> 1, wc = wid & 1;
    const int l15 = lane & 15, lhi = lane >> 4;
    const int lr = lane >> 2, lc = (lane & 3) * 8;
    const int rb = wid * 32;
    const int n0 = blockIdx.y * 128;

    f32x4 acc[4][4];
#pragma unroll
    for (int i = 0; i < 4; ++i)
#pragma unroll
        for (int j = 0; j < 4; ++j) acc[i][j] = (f32x4){0.f, 0.f, 0.f, 0.f};

    for (int k0 = 0; k0 < KP; k0 += 32) {
        gl16(A  + (ll)(m0 + rb      + lr) * KP + k0 + lc, &stg[0][rb     ][0]);
        gl16(A  + (ll)(m0 + rb + 16 + lr) * KP + k0 + lc, &stg[0][rb + 16][0]);
        gl16(Bh + (ll)(n0 + rb      + lr) * KP + k0 + lc, &stg[1][rb     ][0]);
        gl16(Bh + (ll)(n0 + rb + 16 + lr) * KP + k0 + lc, &stg[1][rb + 16][0]);
        gl16(Bl + (ll)(n0 + rb      + lr) * KP + k0 + lc, &stg[2][rb     ][0]);
        gl16(Bl + (ll)(n0 + rb + 16 + lr) * KP + k0 + lc, &stg[2][rb + 16][0]);
        __syncthreads();

        f16x8 av[4];
#pragma unroll
        for (int m = 0; m < 4; ++m)
            av[m] = *(const f16x8*)&stg[0][wr * 64 + m * 16 + l15][lhi * 8];
#pragma unroll
        for (int n = 0; n < 4; ++n) {
            const int r = wc * 64 + n * 16 + l15;
            const f16x8 bh = *(const f16x8*)&stg[1][r][lhi * 8];
            const f16x8 bl = *(const f16x8*)&stg[2][r][lhi * 8];
#pragma unroll
            for (int m = 0; m < 4; ++m) {
                acc[m][n] = __builtin_amdgcn_mfma_f32_16x16x32_f16(av[m], bh, acc[m][n], 0, 0, 0);
                acc[m][n] = __builtin_amdgcn_mfma_f32_16x16x32_f16(av[m], bl, acc[m][n], 0, 0, 0);
            }
        }
        __syncthreads();
    }

#pragma unroll
    for (int m = 0; m < 4; ++m) {
        const int growb = m0 + wr * 64 + m * 16 + lhi * 4;
#pragma unroll
        for (int r = 0; r < 4; ++r) {
            const int grow = growb + r;
            if (grow >= M) continue;
            const float rs = 1.f / (ds[grow] + 1e-9f);
#pragma unroll
            for (int n = 0; n < 4; ++n) {
                const int gcol = n0 + wc * 64 + n * 16 + l15;
                float v = acc[m][n][r] * rs + C[(ll)grow * DD + gcol];
                v = fmaxf(v, 0.f);
                C[(ll)grow * DD + gcol] = v;
                if (EMIT_SPLIT) {
                    const f16 h = (f16)v;
                    const ll oi = ((ll)bz * M + grow) * DD + gcol;
                    Chi[oi] = h;
                    Clo[oi] = (f16)(v - (float)h);
                }
            }
        }
    }
}

// ---------------------------------------------------------------------------
// fp32 -> (hi,lo) f16 split, elementwise (layer-0 activations)
// ---------------------------------------------------------------------------
__global__ __launch_bounds__(256)
void split_f16(const float* __restrict__ x, f16* __restrict__ hi,
               f16* __restrict__ lo, ll n4)
{
    for (ll i = (ll)blockIdx.x * 256 + threadIdx.x; i < n4;
         i += (ll)gridDim.x * 256) {
        float4 v = ((const float4*)x)[i];
        f16 h0 = (f16)v.x, h1 = (f16)v.y, h2 = (f16)v.z, h3 = (f16)v.w;
        f16x4 hv = {h0, h1, h2, h3};
        f16x4 lv = {(f16)(v.x - (float)h0), (f16)(v.y - (float)h1),
                    (f16)(v.z - (float)h2), (f16)(v.w - (float)h3)};
        ((f16x4*)hi)[i] = hv;
        ((f16x4*)lo)[i] = lv;
    }
}

// ---------------------------------------------------------------------------
// Adjacency -> f16, both orientations, padded (0/1 exact in f16):
//   adjF[b][e][n] : [B][AR2][KP2] rows e (agg2 A), cols n zero-padded to 416
//   adjT[b][n][e] : [B][AR1][KP1] rows n (agg1 A), cols e zero-padded to 224
// Unwritten pad ROWS hold finite poison -> reach only output-guarded rows.
// ---------------------------------------------------------------------------
__global__ __launch_bounds__(256)
void adjprep(const float* __restrict__ adj, f16* __restrict__ adjF,
             f16* __restrict__ adjT)
{
    __shared__ float t[32][33];
    const int b = blockIdx.z;
    const int n0 = blockIdx.x * 32, e0 = blockIdx.y * 32;
    const int tx = threadIdx.x & 31, ty = threadIdx.x >> 5;
#pragma unroll
    for (int i = 0; i < 4; ++i) {
        const int e = e0 + ty + i * 8;
        const int n = n0 + tx;
        float v = 0.f;
        if (e < EE && n < NN) v = adj[((ll)b * EE + e) * NN + n];
        t[ty + i * 8][tx] = v;
        adjF[((ll)b * AR2 + e) * KP2 + n] = (f16)v;
    }
    __syncthreads();
#pragma unroll
    for (int i = 0; i < 4; ++i) {
        const int n = n0 + ty + i * 8;
        const int e = e0 + tx;
        adjT[((ll)b * AR1 + n) * KP1 + e] = (f16)t[tx][ty + i * 8];
    }
}

// ---------------------------------------------------------------------------
// Weight prep: transpose [d][e] fp32 -> [e][d] f16 hi/lo, 12 matrices batched
// mats 0..2 = W_ev_ent L0..2, 3..5 = W_ent_ent, 6..8 = W_ent_ev, 9..11 = W_ev_ev
// ---------------------------------------------------------------------------
__global__ __launch_bounds__(256)
void wprep(const float* __restrict__ W0, const float* __restrict__ W1,
           const float* __restrict__ W2, const float* __restrict__ W3,
           f16* __restrict__ hi, f16* __restrict__ lo)
{
    __shared__ float t[32][33];
    const int mat = blockIdx.z;
    const float* Wb = mat < 3 ? W0 : mat < 6 ? W1 : mat < 9 ? W2 : W3;
    const float* W = Wb + (ll)(mat % 3) * DD * DD;
    f16* ho = hi + (ll)mat * DD * DD;
    f16* lp = lo + (ll)mat * DD * DD;
    const int tx = threadIdx.x & 31, ty = threadIdx.x >> 5;
    const int x0 = blockIdx.x * 32, y0 = blockIdx.y * 32;
#pragma unroll
    for (int i = 0; i < 4; ++i)
        t[ty + i * 8][tx] = W[(ll)(y0 + ty + i * 8) * DD + x0 + tx];
    __syncthreads();
#pragma unroll
    for (int i = 0; i < 4; ++i) {
        const float v = t[tx][ty + i * 8];
        const f16 h = (f16)v;
        const ll idx = (ll)(x0 + ty + i * 8) * DD + y0 + tx;
        ho[idx] = h;
        lp[idx] = (f16)(v - (float)h);
    }
}

// ---------------------------------------------------------------------------
// Adjacency degree sums (denominators for the folded normalization)
// ---------------------------------------------------------------------------
__global__ __launch_bounds__(256)
void adj_sums(const float* __restrict__ adj, float* __restrict__ rowsum,
              float* __restrict__ colsum)
{
    const int b = blockIdx.x, tid = threadIdx.x;
    for (int e = tid; e < EE; e += 256) {
        const float* r = adj + ((ll)b * EE + e) * NN;
        float s = 0.f;
        for (int n = 0; n < NN; n += 4) {
            float4 v = *reinterpret_cast<const float4*>(r + n);
            s += v.x + v.y + v.z + v.w;
        }
        rowsum[b * EE + e] = s;
    }
    for (int n = tid; n < NN; n += 256) {
        float s = 0.f;
        for (int e = 0; e < EE; ++e) s += adj[((ll)b * EE + e) * NN + n];
        colsum[b * NN + n] = s;
    }
}

// ---------------------------------------------------------------------------
// Fused attention (both heads, blockIdx.y selects ev/ent):
//   att = softmax(x . (W @ sr) + b.sr)  over M
// ---------------------------------------------------------------------------
__global__ __launch_bounds__(256)
void attn2(const float* __restrict__ ev, const float* __restrict__ ent,
           const float* __restrict__ Wev, const float* __restrict__ bev,
           const float* __restrict__ Went, const float* __restrict__ bent,
           const float* __restrict__ sr,
           float* __restrict__ ev_att, float* __restrict__ ent_att)
{
    __shared__ float s_sr[DD];
    __shared__ float s_u[DD];
    __shared__ float s_log[NN];
    __shared__ float s_red[256];
    const int b = blockIdx.x, head = blockIdx.y, tid = threadIdx.x;
    const float* x = head ? ent : ev;
    const float* W = head ? Went : Wev;
    const float* bv = head ? bent : bev;
    float* att = head ? ent_att : ev_att;
    const int M = head ? NN : EE;

    for (int d = tid; d < DD; d += 256) s_sr[d] = sr[b * DD + d];
    __syncthreads();

    float cpart = 0.f;
    for (int d = tid; d < DD; d += 256) cpart += bv[d] * s_sr[d];
    for (int d = tid; d < DD; d += 256) {
        const float* wr = W + (ll)d * DD;
        float a = 0.f;
        for (int e = 0; e < DD; e += 4) {
            float4 w = *reinterpret_cast<const float4*>(wr + e);
            float4 s = *reinterpret_cast<const float4*>(s_sr + e);
            a += w.x * s.x + w.y * s.y + w.z * s.z + w.w * s.w;
        }
        s_u[d] = a;
    }
    s_red[tid] = cpart;
    __syncthreads();
    for (int off = 128; off > 0; off >>= 1) {
        if (tid < off) s_red[tid] += s_red[tid + off];
        __syncthreads();
    }
    const float c = s_red[0];
    __syncthreads();

    for (int m = tid; m < M; m += 256) {
        const float* xr = x + ((ll)b * M + m) * DD;
        float a = c;
        for (int e = 0; e < DD; e += 4) {
            float4 xv = *reinterpret_cast<const float4*>(xr + e);
            float4 uv = *reinterpret_cast<const float4*>(s_u + e);
            a += xv.x * uv.x + xv.y * uv.y + xv.z * uv.z + xv.w * uv.w;
        }
        s_log[m] = a;
    }
    __syncthreads();

    float mx = -1e30f;
    for (int m = tid; m < M; m += 256) mx = fmaxf(mx, s_log[m]);
    s_red[tid] = mx;
    __syncthreads();
    for (int off = 128; off > 0; off >>= 1) {
        if (tid < off) s_red[tid] = fmaxf(s_red[tid], s_red[tid + off]);
        __syncthreads();
    }
    const float smax = s_red[0];
    __syncthreads();

    float sum = 0.f;
    for (int m = tid; m < M; m += 256) {
        float e_ = expf(s_log[m] - smax);
        s_log[m] = e_;
        sum += e_;
    }
    s_red[tid] = sum;
    __syncthreads();
    for (int off = 128; off > 0; off >>= 1) {
        if (tid < off) s_red[tid] += s_red[tid + off];
        __syncthreads();
    }
    const float inv = 1.f / s_red[0];
    __syncthreads();
    for (int m = tid; m < M; m += 256) att[b * M + m] = s_log[m] * inv;
}

// ---------------------------------------------------------------------------
// Bilinear heads: out = x . (W @ sr) + bias ; block per (batch, head)
// ---------------------------------------------------------------------------
__global__ __launch_bounds__(256)
void heads_kernel(const float* __restrict__ ent, const float* __restrict__ ev,
                  const float* __restrict__ sr, const float* __restrict__ W_ans,
                  const float* __restrict__ b_ans, const float* __restrict__ W_evb,
                  const float* __restrict__ b_evb, float* __restrict__ out)
{
    __shared__ float s_sr[DD];
    __shared__ float s_v[DD];
    const int b = blockIdx.x, head = blockIdx.y, tid = threadIdx.x;
    const float* W = head ? W_evb : W_ans;
    const float* x = head ? ev : ent;
    const int M = head ? EE : NN;
    const float bias = head ? b_evb[0] : b_ans[0];
    float* o = out + (ll)b * (NN + EE) + (head ? NN : 0);

    for (int d = tid; d < DD; d += 256) s_sr[d] = sr[b * DD + d];
    __syncthreads();
    for (int d = tid; d < DD; d += 256) {
        const float* wr = W + (ll)d * DD;
        float a = 0.f;
        for (int e = 0; e < DD; e += 4) {
            float4 w = *reinterpret_cast<const float4*>(wr + e);
            float4 s = *reinterpret_cast<const float4*>(s_sr + e);
            a += w.x * s.x + w.y * s.y + w.z * s.z + w.w * s.w;
        }
        s_v[d] = a;
    }
    __syncthreads();
    for (int m = tid; m < M; m += 256) {
        const float* xr = x + ((ll)b * M + m) * DD;
        float a = bias;
        for (int e = 0; e < DD; e += 4) {
            float4 xv = *reinterpret_cast<const float4*>(xr + e);
            float4 vv = *reinterpret_cast<const float4*>(s_v + e);
            a += xv.x * vv.x + xv.y * vv.y + xv.z * vv.z + xv.w * vv.w;
        }
        o[m] = a;
    }
}

// ---------------------------------------------------------------------------
extern "C" void kernel_launch(void* const* d_in, const int* in_sizes, int n_in,
                              void* d_out, int out_size, void* d_ws, size_t ws_size,
                              hipStream_t stream)
{
    const float* ent_emb = (const float*)d_in[0];
    const float* ev_emb  = (const float*)d_in[1];
    const float* sr      = (const float*)d_in[2];
    const float* adj     = (const float*)d_in[3];
    const float* W_ev_att  = (const float*)d_in[4];
    const float* b_ev_att  = (const float*)d_in[5];
    const float* W_ent_att = (const float*)d_in[6];
    const float* b_ent_att = (const float*)d_in[7];
    const float* W_ev_ent  = (const float*)d_in[8];
    const float* b_ev_ent  = (const float*)d_in[9];
    const float* W_ent_ent = (const float*)d_in[10];
    const float* b_ent_ent = (const float*)d_in[11];
    const float* W_ent_ev  = (const float*)d_in[12];
    const float* b_ent_ev  = (const float*)d_in[13];
    const float* W_ev_ev   = (const float*)d_in[14];
    const float* b_ev_ev   = (const float*)d_in[15];
    const float* W_ans = (const float*)d_in[16];
    const float* b_ans = (const float*)d_in[17];
    const float* W_evb = (const float*)d_in[18];
    const float* b_evb = (const float*)d_in[19];

    float* ws = (float*)d_ws;
    ll o = 0;
    float* ent_ws = ws + o; o += (ll)BB * NN * DD;
    float* ev_ws  = ws + o; o += (ll)BB * EE * DD;
    float* ev_att  = ws + o; o += BB * EE;
    float* ent_att = ws + o; o += BB * NN;
    float* rowsum  = ws + o; o += BB * EE;
    float* colsum  = ws + o; o += BB * NN;
    o = (o + 3) & ~3LL;                              // 16B-align f16 region
    f16* fb = (f16*)(ws + o);
    ll o2 = 0;
    f16* enthi = fb + o2; o2 += (ll)BB * NN * DD;
    f16* entlo = fb + o2; o2 += (ll)BB * NN * DD;
    f16* evhi  = fb + o2; o2 += (ll)BB * EE * DD;
    f16* evlo  = fb + o2; o2 += (ll)BB * EE * DD;
    f16* WThi  = fb + o2; o2 += (ll)12 * DD * DD;
    f16* WTlo  = fb + o2; o2 += (ll)12 * DD * DD;
    f16* adjF  = fb + o2; o2 += (ll)BB * AR2 * KP2;
    f16* adjT  = fb + o2; o2 += (ll)BB * AR1 * KP1;
    f16* MevTh = fb + o2; o2 += (ll)BB * DD * KP1;
    f16* MevTl = fb + o2; o2 += (ll)BB * DD * KP1;
    f16* MentTh = fb + o2; o2 += (ll)BB * DD * KP2;
    f16* MentTl = fb + o2; o2 += (ll)BB * DD * KP2;

    const ll WS = (ll)DD * DD;
    const ll MS = (ll)DD * DD;

    adj_sums<<<BB, 256, 0, stream>>>(adj, rowsum, colsum);
    adjprep<<<dim3(KP2 / 32, KP1 / 32, BB), 256, 0, stream>>>(adj, adjF, adjT);
    wprep<<<dim3(DD / 32, DD / 32, 12), 256, 0, stream>>>(
        W_ev_ent, W_ent_ent, W_ent_ev, W_ev_ev, WThi, WTlo);
    split_f16<<<1024, 256, 0, stream>>>(ent_emb, enthi, entlo, (ll)BB * NN * DD / 4);
    split_f16<<<1024, 256, 0, stream>>>(ev_emb, evhi, evlo, (ll)BB * EE * DD / 4);

    const float* entc = ent_emb;
    const float* evc  = ev_emb;

    const dim3 gL(BB * NN / 128 + BB * EE / 128, 2 * DD / 128);  // 150 x 12
    const dim3 gAm(AR1 / 128 + AR2 / 128, DD / 128, BB);         // 6 x 6 x 32

    for (int i = 0; i < LL; ++i) {
        attn2<<<dim3(BB, 2), 256, 0, stream>>>(
            evc, entc, W_ev_att + i * WS, b_ev_att + i * DD,
            W_ent_att + i * WS, b_ent_att + i * DD, sr, ev_att, ent_att);

        // all four relation linears in one launch
        mfma_lin4<<<gL, 256, 0, stream>>>(
            enthi, entlo, evhi, evlo,
            WThi + (3 + i) * MS, WTlo + (3 + i) * MS, b_ent_ent + i * DD,  // ent self
            WThi + (6 + i) * MS, WTlo + (6 + i) * MS, b_ent_ev + i * DD,   // ent msg
            WThi + (9 + i) * MS, WTlo + (9 + i) * MS, b_ev_ev + i * DD,    // ev self
            WThi + (0 + i) * MS, WTlo + (0 + i) * MS, b_ev_ent + i * DD,   // ev msg
            ent_att, ev_att, ent_ws, ev_ws,
            MentTh, MentTl, MevTh, MevTl);

        // merged aggregation: ent_ws = relu(ent_ws + (adjT@MevT^T)/colsum)
        //                     ev_ws  = relu(ev_ws  + (adjF@MentT^T)/rowsum)
        if (i < LL - 1) {
            mfma_agg2<true><<<gAm, 256, 0, stream>>>(
                adjT, MevTh, MevTl, colsum, ent_ws, enthi, entlo,
                adjF, MentTh, MentTl, rowsum, ev_ws, evhi, evlo);
        } else {
            mfma_agg2<false><<<gAm, 256, 0, stream>>>(
                adjT, MevTh, MevTl, colsum, ent_ws, nullptr, nullptr,
                adjF, MentTh, MentTl, rowsum, ev_ws, nullptr, nullptr);
        }

        entc = ent_ws;
        evc  = ev_ws;
    }

    heads_kernel<<<dim3(BB, 2), 256, 0, stream>>>(entc, evc, sr, W_ans, b_ans,
                                                  W_evb, b_evb, (float*)d_out);
}

// Round 10
// 1536.557 us; speedup vs baseline: 1.1472x; 1.1199x over previous
//
#include <hip/hip_runtime.h>
#include <cmath>

#define DD 768
#define BB 32
#define NN 400
#define EE 200
#define LL 3

// padded dims for MFMA aggregation (K multiples of 32; A-row pads to tile)
#define KP1 224   // E padded (agg1 K)
#define KP2 416   // N padded (agg2 K)
#define AR1 512   // adjT row pad (N-side rows, 4 tiles of 128)
#define AR2 256   // adjF row pad (E-side rows, 2 tiles of 128)

typedef long long ll;
typedef _Float16 f16;
typedef f16 f16x8 __attribute__((ext_vector_type(8)));
typedef f16 f16x4 __attribute__((ext_vector_type(4)));
typedef float f32x4 __attribute__((ext_vector_type(4)));

// async global->LDS, 16B per lane; LDS dest is wave-uniform base + lane*16
__device__ __forceinline__ void gl16(const void* g, void* l) {
    __builtin_amdgcn_global_load_lds(
        (const __attribute__((address_space(1))) unsigned int*)g,
        (__attribute__((address_space(3))) unsigned int*)l, 16, 0, 0);
}

// ---------------------------------------------------------------------------
// Merged split-fp16 MFMA GEMM (ALL FOUR relation linears in one launch):
//   blockIdx.x <  100 : ent activations (M=12800)   else ev (M=6400)
//   blockIdx.y <  6   : "self" path  C = A @ Ws + bs            (fp32 out)
//   blockIdx.y >= 6   : "msg"  path  T = T(split((A @ Wm + bm) * att_row))
// 3-term Markidis (hi*hi + hi*lo + lo*hi, fp32 accum -> ~1e-6 rel error).
// 2-phase double-buffered prefetch (T3 minimum): issue next tile's
// global_load_lds BEFORE computing current tile; ONE barrier per K-step.
// The compiler's vmcnt drain before s_barrier then lands after compute has
// hidden the HBM/L2 latency (previous structure exposed it every step).
// ---------------------------------------------------------------------------
__global__ __launch_bounds__(256)
void mfma_lin4(const f16* __restrict__ entAh, const f16* __restrict__ entAl,
               const f16* __restrict__ evAh,  const f16* __restrict__ evAl,
               const f16* __restrict__ Wh_es, const f16* __restrict__ Wl_es,
               const float* __restrict__ b_es,
               const f16* __restrict__ Wh_em, const f16* __restrict__ Wl_em,
               const float* __restrict__ b_em,
               const f16* __restrict__ Wh_vs, const f16* __restrict__ Wl_vs,
               const float* __restrict__ b_vs,
               const f16* __restrict__ Wh_vm, const f16* __restrict__ Wl_vm,
               const float* __restrict__ b_vm,
               const float* __restrict__ ent_att, const float* __restrict__ ev_att,
               float* __restrict__ Cent, float* __restrict__ Cev,
               f16* __restrict__ TentH, f16* __restrict__ TentL,
               f16* __restrict__ TevH,  f16* __restrict__ TevL)
{
    __shared__ __align__(16) union SM {
        f16 stg[2][4][128][32];   // dbuf x {Ah,Al,Bh,Bl} : 65536 B (linear!)
        f16 tb[128][136];         // transpose buffer     : 34816 B
    } sm;

    const int bx = blockIdx.x;
    const bool isEnt = bx < (BB * NN / 128);
    const int xl = isEnt ? bx : bx - BB * NN / 128;
    const bool msg = (blockIdx.y >= DD / 128);
    const int n0 = (msg ? blockIdx.y - DD / 128 : blockIdx.y) * 128;
    const int m0 = xl * 128;

    const f16* __restrict__ Ah = isEnt ? entAh : evAh;
    const f16* __restrict__ Al = isEnt ? entAl : evAl;
    const f16* __restrict__ Wh = isEnt ? (msg ? Wh_em : Wh_es) : (msg ? Wh_vm : Wh_vs);
    const f16* __restrict__ Wl = isEnt ? (msg ? Wl_em : Wl_es) : (msg ? Wl_vm : Wl_vs);
    const float* __restrict__ bias = isEnt ? (msg ? b_em : b_es) : (msg ? b_vm : b_vs);
    const float* __restrict__ rsc = isEnt ? ent_att : ev_att;
    float* __restrict__ C = isEnt ? Cent : Cev;

    const int tid = threadIdx.x;
    const int lane = tid & 63, wid = tid >> 6;
    const int wr = wid >> 1, wc = wid & 1;
    const int l15 = lane & 15, lhi = lane >> 4;
    const int lr = lane >> 2;            // 0..15 row within 16-row chunk
    const int lc = (lane & 3) * 8;       // f16 col within 32-f16 row
    const int rb = wid * 32;             // wave's chunk row base (uniform)

    f32x4 acc[4][4];
#pragma unroll
    for (int i = 0; i < 4; ++i)
#pragma unroll
        for (int j = 0; j < 4; ++j) acc[i][j] = (f32x4){0.f, 0.f, 0.f, 0.f};

    auto STAGE = [&](int bsel, int k0) {
        gl16(Ah + (ll)(m0 + rb      + lr) * DD + k0 + lc, &sm.stg[bsel][0][rb     ][0]);
        gl16(Ah + (ll)(m0 + rb + 16 + lr) * DD + k0 + lc, &sm.stg[bsel][0][rb + 16][0]);
        gl16(Al + (ll)(m0 + rb      + lr) * DD + k0 + lc, &sm.stg[bsel][1][rb     ][0]);
        gl16(Al + (ll)(m0 + rb + 16 + lr) * DD + k0 + lc, &sm.stg[bsel][1][rb + 16][0]);
        gl16(Wh + (ll)(n0 + rb      + lr) * DD + k0 + lc, &sm.stg[bsel][2][rb     ][0]);
        gl16(Wh + (ll)(n0 + rb + 16 + lr) * DD + k0 + lc, &sm.stg[bsel][2][rb + 16][0]);
        gl16(Wl + (ll)(n0 + rb      + lr) * DD + k0 + lc, &sm.stg[bsel][3][rb     ][0]);
        gl16(Wl + (ll)(n0 + rb + 16 + lr) * DD + k0 + lc, &sm.stg[bsel][3][rb + 16][0]);
    };

    const int nt = DD / 32;   // 24 K-steps
    STAGE(0, 0);
    for (int t = 0; t < nt; ++t) {
        __syncthreads();                     // drains stage(t); buf[t&1] valid
        if (t + 1 < nt) STAGE((t + 1) & 1, (t + 1) * 32);   // async prefetch
        __builtin_amdgcn_sched_barrier(0);   // pin issue order: loads first
        const int bsel = t & 1;

        f16x8 ah[4], al[4];
#pragma unroll
        for (int m = 0; m < 4; ++m) {
            const int r = wr * 64 + m * 16 + l15;
            ah[m] = *(const f16x8*)&sm.stg[bsel][0][r][lhi * 8];
            al[m] = *(const f16x8*)&sm.stg[bsel][1][r][lhi * 8];
        }
#pragma unroll
        for (int n = 0; n < 4; ++n) {
            const int r = wc * 64 + n * 16 + l15;
            const f16x8 bh = *(const f16x8*)&sm.stg[bsel][2][r][lhi * 8];
            const f16x8 bl = *(const f16x8*)&sm.stg[bsel][3][r][lhi * 8];
#pragma unroll
            for (int m = 0; m < 4; ++m) {
                acc[m][n] = __builtin_amdgcn_mfma_f32_16x16x32_f16(ah[m], bh, acc[m][n], 0, 0, 0);
                acc[m][n] = __builtin_amdgcn_mfma_f32_16x16x32_f16(ah[m], bl, acc[m][n], 0, 0, 0);
                acc[m][n] = __builtin_amdgcn_mfma_f32_16x16x32_f16(al[m], bh, acc[m][n], 0, 0, 0);
            }
        }
    }

    // fold bias (+ attention row-scale on msg path); fp32 C write (self path)
#pragma unroll
    for (int m = 0; m < 4; ++m) {
        const int growb = m0 + wr * 64 + m * 16 + lhi * 4;
#pragma unroll
        for (int r = 0; r < 4; ++r) {
            const int grow = growb + r;
            const float rs = msg ? rsc[grow] : 1.f;
#pragma unroll
            for (int n = 0; n < 4; ++n) {
                const int gcol = n0 + wc * 64 + n * 16 + l15;
                float v = acc[m][n][r] + bias[gcol];
                if (msg) v *= rs;
                acc[m][n][r] = v;
                if (!msg) C[(ll)grow * DD + gcol] = v;
            }
        }
    }

    if (msg) {
        f16* __restrict__ ThP = isEnt ? TentH : TevH;
        f16* __restrict__ TlP = isEnt ? TentL : TevL;
        const int KPV = isEnt ? KP2 : KP1;
        // two-phase LDS transpose (hi then lo), coalesced global emit
        for (int ph = 0; ph < 2; ++ph) {
            __syncthreads();   // all waves' ds_reads done before tb overwrite
#pragma unroll
            for (int m = 0; m < 4; ++m) {
#pragma unroll
                for (int n = 0; n < 4; ++n) {
                    const int col = wc * 64 + n * 16 + l15;      // output col (d)
                    const int rowb = wr * 64 + m * 16 + lhi * 4; // output row (k)
                    f16x4 pv;
#pragma unroll
                    for (int r = 0; r < 4; ++r) {
                        const float v = acc[m][n][r];
                        const f16 h = (f16)v;
                        pv[r] = (ph == 0) ? h : (f16)(v - (float)h);
                    }
                    *(f16x4*)&sm.tb[col][rowb] = pv;   // tb[d_local][k_local]
                }
            }
            __syncthreads();
            f16* T = ph ? TlP : ThP;
            const int dl = tid >> 5;            // 0..7
            const int k4 = (tid & 31) * 4;      // 0..124, chunk of 4 k
#pragma unroll
            for (int it = 0; it < 16; ++it) {
                const int d_local = dl + it * 8;
                const f16x4 v = *(const f16x4*)&sm.tb[d_local][k4];
                const int gk = m0 + k4;         // global row index (b*MROWS+k)
                const int b = isEnt ? (gk / NN) : (gk / EE);  // literal -> magic mul
                const int kk = gk - b * (isEnt ? NN : EE);    // chunks never cross batch
                *(f16x4*)(T + ((ll)b * DD + (n0 + d_local)) * KPV + kk) = v;
            }
        }
    }
}

// ---------------------------------------------------------------------------
// Merged MFMA aggregation (both directions in one launch):
//   blockIdx.x <  4 : ent update: C1 = relu(C1 + (adjT @ MevT^T)/colsum)
//   blockIdx.x >= 4 : ev  update: C2 = relu(C2 + (adjF @ MentT^T)/rowsum)
// A = 0/1 adjacency in f16 (exact, single term); B = hi/lo split (2-term).
// Same 2-phase double-buffered prefetch as mfma_lin4.
// ---------------------------------------------------------------------------
template<bool EMIT_SPLIT>
__global__ __launch_bounds__(256)
void mfma_agg2(const f16* __restrict__ A1, const f16* __restrict__ B1h,
               const f16* __restrict__ B1l, const float* __restrict__ ds1,
               float* __restrict__ C1, f16* __restrict__ C1hi, f16* __restrict__ C1lo,
               const f16* __restrict__ A2, const f16* __restrict__ B2h,
               const f16* __restrict__ B2l, const float* __restrict__ ds2,
               float* __restrict__ C2, f16* __restrict__ C2hi, f16* __restrict__ C2lo)
{
    __shared__ __align__(16) f16 stg[2][3][128][32];   // dbuf x {A,Bh,Bl} : 49152 B
    const int bz = blockIdx.z;
    const bool first = (blockIdx.x < AR1 / 128);

    const f16* A;
    const f16* Bh;
    const f16* Bl;
    const float* ds;
    float* C;
    f16* Chi;
    f16* Clo;
    int M, KP, m0;
    if (first) {
        A = A1 + (ll)bz * AR1 * KP1;
        Bh = B1h + (ll)bz * DD * KP1;
        Bl = B1l + (ll)bz * DD * KP1;
        ds = ds1 + (ll)bz * NN;
        C = C1 + (ll)bz * NN * DD;
        Chi = C1hi; Clo = C1lo;
        M = NN; KP = KP1;
        m0 = blockIdx.x * 128;
    } else {
        A = A2 + (ll)bz * AR2 * KP2;
        Bh = B2h + (ll)bz * DD * KP2;
        Bl = B2l + (ll)bz * DD * KP2;
        ds = ds2 + (ll)bz * EE;
        C = C2 + (ll)bz * EE * DD;
        Chi = C2hi; Clo = C2lo;
        M = EE; KP = KP2;
        m0 = (blockIdx.x - AR1 / 128) * 128;
    }

    const int tid = threadIdx.x;
    const int lane = tid & 63, wid = tid >> 6;
    const int wr = wid >> 1, wc = wid & 1;
    const int l15 = lane & 15, lhi = lane >> 4;
    const int lr = lane >> 2, lc = (lane & 3) * 8;
    const int rb = wid * 32;
    const int n0 = blockIdx.y * 128;

    f32x4 acc[4][4];
#pragma unroll
    for (int i = 0; i < 4; ++i)
#pragma unroll
        for (int j = 0; j < 4; ++j) acc[i][j] = (f32x4){0.f, 0.f, 0.f, 0.f};

    auto STAGE = [&](int bsel, int k0) {
        gl16(A  + (ll)(m0 + rb      + lr) * KP + k0 + lc, &stg[bsel][0][rb     ][0]);
        gl16(A  + (ll)(m0 + rb + 16 + lr) * KP + k0 + lc, &stg[bsel][0][rb + 16][0]);
        gl16(Bh + (ll)(n0 + rb      + lr) * KP + k0 + lc, &stg[bsel][1][rb     ][0]);
        gl16(Bh + (ll)(n0 + rb + 16 + lr) * KP + k0 + lc, &stg[bsel][1][rb + 16][0]);
        gl16(Bl + (ll)(n0 + rb      + lr) * KP + k0 + lc, &stg[bsel][2][rb     ][0]);
        gl16(Bl + (ll)(n0 + rb + 16 + lr) * KP + k0 + lc, &stg[bsel][2][rb + 16][0]);
    };

    const int nt = KP / 32;
    STAGE(0, 0);
    for (int t = 0; t < nt; ++t) {
        __syncthreads();
        if (t + 1 < nt) STAGE((t + 1) & 1, (t + 1) * 32);
        __builtin_amdgcn_sched_barrier(0);
        const int bsel = t & 1;

        f16x8 av[4];
#pragma unroll
        for (int m = 0; m < 4; ++m)
            av[m] = *(const f16x8*)&stg[bsel][0][wr * 64 + m * 16 + l15][lhi * 8];
#pragma unroll
        for (int n = 0; n < 4; ++n) {
            const int r = wc * 64 + n * 16 + l15;
            const f16x8 bh = *(const f16x8*)&stg[bsel][1][r][lhi * 8];
            const f16x8 bl = *(const f16x8*)&stg[bsel][2][r][lhi * 8];
#pragma unroll
            for (int m = 0; m < 4; ++m) {
                acc[m][n] = __builtin_amdgcn_mfma_f32_16x16x32_f16(av[m], bh, acc[m][n], 0, 0, 0);
                acc[m][n] = __builtin_amdgcn_mfma_f32_16x16x32_f16(av[m], bl, acc[m][n], 0, 0, 0);
            }
        }
    }

#pragma unroll
    for (int m = 0; m < 4; ++m) {
        const int growb = m0 + wr * 64 + m * 16 + lhi * 4;
#pragma unroll
        for (int r = 0; r < 4; ++r) {
            const int grow = growb + r;
            if (grow >= M) continue;
            const float rs = 1.f / (ds[grow] + 1e-9f);
#pragma unroll
            for (int n = 0; n < 4; ++n) {
                const int gcol = n0 + wc * 64 + n * 16 + l15;
                float v = acc[m][n][r] * rs + C[(ll)grow * DD + gcol];
                v = fmaxf(v, 0.f);
                C[(ll)grow * DD + gcol] = v;
                if (EMIT_SPLIT) {
                    const f16 h = (f16)v;
                    const ll oi = ((ll)bz * M + grow) * DD + gcol;
                    Chi[oi] = h;
                    Clo[oi] = (f16)(v - (float)h);
                }
            }
        }
    }
}

// ---------------------------------------------------------------------------
// fp32 -> (hi,lo) f16 split, elementwise (layer-0 activations)
// ---------------------------------------------------------------------------
__global__ __launch_bounds__(256)
void split_f16(const float* __restrict__ x, f16* __restrict__ hi,
               f16* __restrict__ lo, ll n4)
{
    for (ll i = (ll)blockIdx.x * 256 + threadIdx.x; i < n4;
         i += (ll)gridDim.x * 256) {
        float4 v = ((const float4*)x)[i];
        f16 h0 = (f16)v.x, h1 = (f16)v.y, h2 = (f16)v.z, h3 = (f16)v.w;
        f16x4 hv = {h0, h1, h2, h3};
        f16x4 lv = {(f16)(v.x - (float)h0), (f16)(v.y - (float)h1),
                    (f16)(v.z - (float)h2), (f16)(v.w - (float)h3)};
        ((f16x4*)hi)[i] = hv;
        ((f16x4*)lo)[i] = lv;
    }
}

// ---------------------------------------------------------------------------
// Adjacency -> f16, both orientations, padded (0/1 exact in f16):
//   adjF[b][e][n] : [B][AR2][KP2] rows e (agg2 A), cols n zero-padded to 416
//   adjT[b][n][e] : [B][AR1][KP1] rows n (agg1 A), cols e zero-padded to 224
// Unwritten pad ROWS hold finite poison -> reach only output-guarded rows.
// ---------------------------------------------------------------------------
__global__ __launch_bounds__(256)
void adjprep(const float* __restrict__ adj, f16* __restrict__ adjF,
             f16* __restrict__ adjT)
{
    __shared__ float t[32][33];
    const int b = blockIdx.z;
    const int n0 = blockIdx.x * 32, e0 = blockIdx.y * 32;
    const int tx = threadIdx.x & 31, ty = threadIdx.x >> 5;
#pragma unroll
    for (int i = 0; i < 4; ++i) {
        const int e = e0 + ty + i * 8;
        const int n = n0 + tx;
        float v = 0.f;
        if (e < EE && n < NN) v = adj[((ll)b * EE + e) * NN + n];
        t[ty + i * 8][tx] = v;
        adjF[((ll)b * AR2 + e) * KP2 + n] = (f16)v;
    }
    __syncthreads();
#pragma unroll
    for (int i = 0; i < 4; ++i) {
        const int n = n0 + ty + i * 8;
        const int e = e0 + tx;
        adjT[((ll)b * AR1 + n) * KP1 + e] = (f16)t[tx][ty + i * 8];
    }
}

// ---------------------------------------------------------------------------
// Weight prep: transpose [d][e] fp32 -> [e][d] f16 hi/lo, 12 matrices batched
// mats 0..2 = W_ev_ent L0..2, 3..5 = W_ent_ent, 6..8 = W_ent_ev, 9..11 = W_ev_ev
// ---------------------------------------------------------------------------
__global__ __launch_bounds__(256)
void wprep(const float* __restrict__ W0, const float* __restrict__ W1,
           const float* __restrict__ W2, const float* __restrict__ W3,
           f16* __restrict__ hi, f16* __restrict__ lo)
{
    __shared__ float t[32][33];
    const int mat = blockIdx.z;
    const float* Wb = mat < 3 ? W0 : mat < 6 ? W1 : mat < 9 ? W2 : W3;
    const float* W = Wb + (ll)(mat % 3) * DD * DD;
    f16* ho = hi + (ll)mat * DD * DD;
    f16* lp = lo + (ll)mat * DD * DD;
    const int tx = threadIdx.x & 31, ty = threadIdx.x >> 5;
    const int x0 = blockIdx.x * 32, y0 = blockIdx.y * 32;
#pragma unroll
    for (int i = 0; i < 4; ++i)
        t[ty + i * 8][tx] = W[(ll)(y0 + ty + i * 8) * DD + x0 + tx];
    __syncthreads();
#pragma unroll
    for (int i = 0; i < 4; ++i) {
        const float v = t[tx][ty + i * 8];
        const f16 h = (f16)v;
        const ll idx = (ll)(x0 + ty + i * 8) * DD + y0 + tx;
        ho[idx] = h;
        lp[idx] = (f16)(v - (float)h);
    }
}

// ---------------------------------------------------------------------------
// Adjacency degree sums (denominators for the folded normalization)
// ---------------------------------------------------------------------------
__global__ __launch_bounds__(256)
void adj_sums(const float* __restrict__ adj, float* __restrict__ rowsum,
              float* __restrict__ colsum)
{
    const int b = blockIdx.x, tid = threadIdx.x;
    for (int e = tid; e < EE; e += 256) {
        const float* r = adj + ((ll)b * EE + e) * NN;
        float s = 0.f;
        for (int n = 0; n < NN; n += 4) {
            float4 v = *reinterpret_cast<const float4*>(r + n);
            s += v.x + v.y + v.z + v.w;
        }
        rowsum[b * EE + e] = s;
    }
    for (int n = tid; n < NN; n += 256) {
        float s = 0.f;
        for (int e = 0; e < EE; ++e) s += adj[((ll)b * EE + e) * NN + n];
        colsum[b * NN + n] = s;
    }
}

// ---------------------------------------------------------------------------
// Fused attention (both heads, blockIdx.y selects ev/ent):
//   att = softmax(x . (W @ sr) + b.sr)  over M
// ---------------------------------------------------------------------------
__global__ __launch_bounds__(256)
void attn2(const float* __restrict__ ev, const float* __restrict__ ent,
           const float* __restrict__ Wev, const float* __restrict__ bev,
           const float* __restrict__ Went, const float* __restrict__ bent,
           const float* __restrict__ sr,
           float* __restrict__ ev_att, float* __restrict__ ent_att)
{
    __shared__ float s_sr[DD];
    __shared__ float s_u[DD];
    __shared__ float s_log[NN];
    __shared__ float s_red[256];
    const int b = blockIdx.x, head = blockIdx.y, tid = threadIdx.x;
    const float* x = head ? ent : ev;
    const float* W = head ? Went : Wev;
    const float* bv = head ? bent : bev;
    float* att = head ? ent_att : ev_att;
    const int M = head ? NN : EE;

    for (int d = tid; d < DD; d += 256) s_sr[d] = sr[b * DD + d];
    __syncthreads();

    float cpart = 0.f;
    for (int d = tid; d < DD; d += 256) cpart += bv[d] * s_sr[d];
    for (int d = tid; d < DD; d += 256) {
        const float* wr = W + (ll)d * DD;
        float a = 0.f;
        for (int e = 0; e < DD; e += 4) {
            float4 w = *reinterpret_cast<const float4*>(wr + e);
            float4 s = *reinterpret_cast<const float4*>(s_sr + e);
            a += w.x * s.x + w.y * s.y + w.z * s.z + w.w * s.w;
        }
        s_u[d] = a;
    }
    s_red[tid] = cpart;
    __syncthreads();
    for (int off = 128; off > 0; off >>= 1) {
        if (tid < off) s_red[tid] += s_red[tid + off];
        __syncthreads();
    }
    const float c = s_red[0];
    __syncthreads();

    for (int m = tid; m < M; m += 256) {
        const float* xr = x + ((ll)b * M + m) * DD;
        float a = c;
        for (int e = 0; e < DD; e += 4) {
            float4 xv = *reinterpret_cast<const float4*>(xr + e);
            float4 uv = *reinterpret_cast<const float4*>(s_u + e);
            a += xv.x * uv.x + xv.y * uv.y + xv.z * uv.z + xv.w * uv.w;
        }
        s_log[m] = a;
    }
    __syncthreads();

    float mx = -1e30f;
    for (int m = tid; m < M; m += 256) mx = fmaxf(mx, s_log[m]);
    s_red[tid] = mx;
    __syncthreads();
    for (int off = 128; off > 0; off >>= 1) {
        if (tid < off) s_red[tid] = fmaxf(s_red[tid], s_red[tid + off]);
        __syncthreads();
    }
    const float smax = s_red[0];
    __syncthreads();

    float sum = 0.f;
    for (int m = tid; m < M; m += 256) {
        float e_ = expf(s_log[m] - smax);
        s_log[m] = e_;
        sum += e_;
    }
    s_red[tid] = sum;
    __syncthreads();
    for (int off = 128; off > 0; off >>= 1) {
        if (tid < off) s_red[tid] += s_red[tid + off];
        __syncthreads();
    }
    const float inv = 1.f / s_red[0];
    __syncthreads();
    for (int m = tid; m < M; m += 256) att[b * M + m] = s_log[m] * inv;
}

// ---------------------------------------------------------------------------
// Bilinear heads: out = x . (W @ sr) + bias ; block per (batch, head)
// ---------------------------------------------------------------------------
__global__ __launch_bounds__(256)
void heads_kernel(const float* __restrict__ ent, const float* __restrict__ ev,
                  const float* __restrict__ sr, const float* __restrict__ W_ans,
                  const float* __restrict__ b_ans, const float* __restrict__ W_evb,
                  const float* __restrict__ b_evb, float* __restrict__ out)
{
    __shared__ float s_sr[DD];
    __shared__ float s_v[DD];
    const int b = blockIdx.x, head = blockIdx.y, tid = threadIdx.x;
    const float* W = head ? W_evb : W_ans;
    const float* x = head ? ev : ent;
    const int M = head ? EE : NN;
    const float bias = head ? b_evb[0] : b_ans[0];
    float* o = out + (ll)b * (NN + EE) + (head ? NN : 0);

    for (int d = tid; d < DD; d += 256) s_sr[d] = sr[b * DD + d];
    __syncthreads();
    for (int d = tid; d < DD; d += 256) {
        const float* wr = W + (ll)d * DD;
        float a = 0.f;
        for (int e = 0; e < DD; e += 4) {
            float4 w = *reinterpret_cast<const float4*>(wr + e);
            float4 s = *reinterpret_cast<const float4*>(s_sr + e);
            a += w.x * s.x + w.y * s.y + w.z * s.z + w.w * s.w;
        }
        s_v[d] = a;
    }
    __syncthreads();
    for (int m = tid; m < M; m += 256) {
        const float* xr = x + ((ll)b * M + m) * DD;
        float a = bias;
        for (int e = 0; e < DD; e += 4) {
            float4 xv = *reinterpret_cast<const float4*>(xr + e);
            float4 vv = *reinterpret_cast<const float4*>(s_v + e);
            a += xv.x * vv.x + xv.y * vv.y + xv.z * vv.z + xv.w * vv.w;
        }
        o[m] = a;
    }
}

// ---------------------------------------------------------------------------
extern "C" void kernel_launch(void* const* d_in, const int* in_sizes, int n_in,
                              void* d_out, int out_size, void* d_ws, size_t ws_size,
                              hipStream_t stream)
{
    const float* ent_emb = (const float*)d_in[0];
    const float* ev_emb  = (const float*)d_in[1];
    const float* sr      = (const float*)d_in[2];
    const float* adj     = (const float*)d_in[3];
    const float* W_ev_att  = (const float*)d_in[4];
    const float* b_ev_att  = (const float*)d_in[5];
    const float* W_ent_att = (const float*)d_in[6];
    const float* b_ent_att = (const float*)d_in[7];
    const float* W_ev_ent  = (const float*)d_in[8];
    const float* b_ev_ent  = (const float*)d_in[9];
    const float* W_ent_ent = (const float*)d_in[10];
    const float* b_ent_ent = (const float*)d_in[11];
    const float* W_ent_ev  = (const float*)d_in[12];
    const float* b_ent_ev  = (const float*)d_in[13];
    const float* W_ev_ev   = (const float*)d_in[14];
    const float* b_ev_ev   = (const float*)d_in[15];
    const float* W_ans = (const float*)d_in[16];
    const float* b_ans = (const float*)d_in[17];
    const float* W_evb = (const float*)d_in[18];
    const float* b_evb = (const float*)d_in[19];

    float* ws = (float*)d_ws;
    ll o = 0;
    float* ent_ws = ws + o; o += (ll)BB * NN * DD;
    float* ev_ws  = ws + o; o += (ll)BB * EE * DD;
    float* ev_att  = ws + o; o += BB * EE;
    float* ent_att = ws + o; o += BB * NN;
    float* rowsum  = ws + o; o += BB * EE;
    float* colsum  = ws + o; o += BB * NN;
    o = (o + 3) & ~3LL;                              // 16B-align f16 region
    f16* fb = (f16*)(ws + o);
    ll o2 = 0;
    f16* enthi = fb + o2; o2 += (ll)BB * NN * DD;
    f16* entlo = fb + o2; o2 += (ll)BB * NN * DD;
    f16* evhi  = fb + o2; o2 += (ll)BB * EE * DD;
    f16* evlo  = fb + o2; o2 += (ll)BB * EE * DD;
    f16* WThi  = fb + o2; o2 += (ll)12 * DD * DD;
    f16* WTlo  = fb + o2; o2 += (ll)12 * DD * DD;
    f16* adjF  = fb + o2; o2 += (ll)BB * AR2 * KP2;
    f16* adjT  = fb + o2; o2 += (ll)BB * AR1 * KP1;
    f16* MevTh = fb + o2; o2 += (ll)BB * DD * KP1;
    f16* MevTl = fb + o2; o2 += (ll)BB * DD * KP1;
    f16* MentTh = fb + o2; o2 += (ll)BB * DD * KP2;
    f16* MentTl = fb + o2; o2 += (ll)BB * DD * KP2;

    const ll WS = (ll)DD * DD;
    const ll MS = (ll)DD * DD;

    adj_sums<<<BB, 256, 0, stream>>>(adj, rowsum, colsum);
    adjprep<<<dim3(KP2 / 32, KP1 / 32, BB), 256, 0, stream>>>(adj, adjF, adjT);
    wprep<<<dim3(DD / 32, DD / 32, 12), 256, 0, stream>>>(
        W_ev_ent, W_ent_ent, W_ent_ev, W_ev_ev, WThi, WTlo);
    split_f16<<<1024, 256, 0, stream>>>(ent_emb, enthi, entlo, (ll)BB * NN * DD / 4);
    split_f16<<<1024, 256, 0, stream>>>(ev_emb, evhi, evlo, (ll)BB * EE * DD / 4);

    const float* entc = ent_emb;
    const float* evc  = ev_emb;

    const dim3 gL(BB * NN / 128 + BB * EE / 128, 2 * DD / 128);  // 150 x 12
    const dim3 gAm(AR1 / 128 + AR2 / 128, DD / 128, BB);         // 6 x 6 x 32

    for (int i = 0; i < LL; ++i) {
        attn2<<<dim3(BB, 2), 256, 0, stream>>>(
            evc, entc, W_ev_att + i * WS, b_ev_att + i * DD,
            W_ent_att + i * WS, b_ent_att + i * DD, sr, ev_att, ent_att);

        // all four relation linears in one launch
        mfma_lin4<<<gL, 256, 0, stream>>>(
            enthi, entlo, evhi, evlo,
            WThi + (3 + i) * MS, WTlo + (3 + i) * MS, b_ent_ent + i * DD,  // ent self
            WThi + (6 + i) * MS, WTlo + (6 + i) * MS, b_ent_ev + i * DD,   // ent msg
            WThi + (9 + i) * MS, WTlo + (9 + i) * MS, b_ev_ev + i * DD,    // ev self
            WThi + (0 + i) * MS, WTlo + (0 + i) * MS, b_ev_ent + i * DD,   // ev msg
            ent_att, ev_att, ent_ws, ev_ws,
            MentTh, MentTl, MevTh, MevTl);

        // merged aggregation: ent_ws = relu(ent_ws + (adjT@MevT^T)/colsum)
        //                     ev_ws  = relu(ev_ws  + (adjF@MentT^T)/rowsum)
        if (i < LL - 1) {
            mfma_agg2<true><<<gAm, 256, 0, stream>>>(
                adjT, MevTh, MevTl, colsum, ent_ws, enthi, entlo,
                adjF, MentTh, MentTl, rowsum, ev_ws, evhi, evlo);
        } else {
            mfma_agg2<false><<<gAm, 256, 0, stream>>>(
                adjT, MevTh, MevTl, colsum, ent_ws, nullptr, nullptr,
                adjF, MentTh, MentTl, rowsum, ev_ws, nullptr, nullptr);
        }

        entc = ent_ws;
        evc  = ev_ws;
    }

    heads_kernel<<<dim3(BB, 2), 256, 0, stream>>>(entc, evc, sr, W_ans, b_ans,
                                                  W_evb, b_evb, (float*)d_out);
}